// Round 9
// baseline (197.018 us; speedup 1.0000x reference)
//
#include <hip/hip_runtime.h>
#include <cstddef>

#define LN_EPS 1e-5f

__device__ inline float4 ld4(const float* p) { return *reinterpret_cast<const float4*>(p); }
__device__ inline void st4(float* p, float4 v) { *reinterpret_cast<float4*>(p) = v; }

typedef _Float16 h2_t __attribute__((ext_vector_type(2)));

__device__ __forceinline__ unsigned pack2(float x, float y) {
  h2_t h;
  h.x = (_Float16)x;
  h.y = (_Float16)y;
  return __builtin_bit_cast(unsigned, h);
}

// dot2: c += a.x*b.x + a.y*b.y  (f16 inputs, f32 accumulate)
__device__ __forceinline__ float dot2(unsigned a, unsigned b, float c) {
  h2_t ah = __builtin_bit_cast(h2_t, a);
  h2_t bh = __builtin_bit_cast(h2_t, b);
#if __has_builtin(__builtin_amdgcn_fdot2)
  return __builtin_amdgcn_fdot2(ah, bh, c, false);
#else
  return fmaf((float)ah.x, (float)bh.x, fmaf((float)ah.y, (float)bh.y, c));
#endif
}

#define DOT_BLOCK(AtU, WsU)                                                              \
  _Pragma("unroll")                                                                      \
  for (int kk2 = 0; kk2 < 8; ++kk2) {                                                    \
    uint4 a4 = *reinterpret_cast<const uint4*>(&(AtU)[kk2 * 68 + ty * 4]);               \
    uint4 w4 = *reinterpret_cast<const uint4*>(&(WsU)[kk2 * 68 + tx * 4]);               \
    acc[0][0] = dot2(a4.x, w4.x, acc[0][0]); acc[0][1] = dot2(a4.x, w4.y, acc[0][1]);    \
    acc[0][2] = dot2(a4.x, w4.z, acc[0][2]); acc[0][3] = dot2(a4.x, w4.w, acc[0][3]);    \
    acc[1][0] = dot2(a4.y, w4.x, acc[1][0]); acc[1][1] = dot2(a4.y, w4.y, acc[1][1]);    \
    acc[1][2] = dot2(a4.y, w4.z, acc[1][2]); acc[1][3] = dot2(a4.y, w4.w, acc[1][3]);    \
    acc[2][0] = dot2(a4.z, w4.x, acc[2][0]); acc[2][1] = dot2(a4.z, w4.y, acc[2][1]);    \
    acc[2][2] = dot2(a4.z, w4.z, acc[2][2]); acc[2][3] = dot2(a4.z, w4.w, acc[2][3]);    \
    acc[3][0] = dot2(a4.w, w4.x, acc[3][0]); acc[3][1] = dot2(a4.w, w4.y, acc[3][1]);    \
    acc[3][2] = dot2(a4.w, w4.z, acc[3][2]); acc[3][3] = dot2(a4.w, w4.w, acc[3][3]);    \
  }

// ---- 64x64 tile GEMM, f16 LDS, 4x4 micro, KSTEP 16, DOUBLE-BUFFERED (1 barrier/k-step).
// ldsU: 2176 uints = 2 x (At 544 | Ws 544).
__device__ __forceinline__ void gemm16(unsigned* ldsU, const float* __restrict__ A,
                                       const float* __restrict__ W,
                                       const float* __restrict__ bias,
                                       float* __restrict__ dst,
                                       int K, int chunk, int row0, int col0, int k0) {
  const int tid = threadIdx.x;
  const int tx = tid & 15, ty = tid >> 4;
  const int arow = tid >> 2, ak4 = (tid & 3) * 4;
  const int wkk2 = tid >> 4, wc4 = (tid & 15) * 4;  // valid when tid<128
  float acc[4][4] = {{0.f}};
  float4 av = ld4(&A[(size_t)(row0 + arow) * K + k0 + ak4]);
  float4 w0, w1;
  if (tid < 128) {
    w0 = ld4(&W[(size_t)(k0 + 2 * wkk2) * 256 + col0 + wc4]);
    w1 = ld4(&W[(size_t)(k0 + 2 * wkk2 + 1) * 256 + col0 + wc4]);
  }
  // store tile 0 into buf 0 (no prior readers)
  ldsU[(ak4 >> 1) * 68 + arow] = pack2(av.x, av.y);
  ldsU[((ak4 >> 1) + 1) * 68 + arow] = pack2(av.z, av.w);
  if (tid < 128) {
    unsigned* WsU = ldsU + 544;
    WsU[wkk2 * 68 + wc4 + 0] = pack2(w0.x, w1.x);
    WsU[wkk2 * 68 + wc4 + 1] = pack2(w0.y, w1.y);
    WsU[wkk2 * 68 + wc4 + 2] = pack2(w0.z, w1.z);
    WsU[wkk2 * 68 + wc4 + 3] = pack2(w0.w, w1.w);
  }
  if (16 < chunk) {  // prefetch tile 1
    av = ld4(&A[(size_t)(row0 + arow) * K + k0 + 16 + ak4]);
    if (tid < 128) {
      w0 = ld4(&W[(size_t)(k0 + 16 + 2 * wkk2) * 256 + col0 + wc4]);
      w1 = ld4(&W[(size_t)(k0 + 16 + 2 * wkk2 + 1) * 256 + col0 + wc4]);
    }
  }
  __syncthreads();
  int cur = 0;
  for (int ks = 0; ks < chunk; ks += 16) {
    unsigned* AtU = ldsU + cur * 1088;
    unsigned* WsU = AtU + 544;
    DOT_BLOCK(AtU, WsU)
    if (ks + 16 < chunk) {  // store prefetched tile into other buffer (overlaps compute)
      unsigned* AtN = ldsU + (cur ^ 1) * 1088;
      unsigned* WsN = AtN + 544;
      AtN[(ak4 >> 1) * 68 + arow] = pack2(av.x, av.y);
      AtN[((ak4 >> 1) + 1) * 68 + arow] = pack2(av.z, av.w);
      if (tid < 128) {
        WsN[wkk2 * 68 + wc4 + 0] = pack2(w0.x, w1.x);
        WsN[wkk2 * 68 + wc4 + 1] = pack2(w0.y, w1.y);
        WsN[wkk2 * 68 + wc4 + 2] = pack2(w0.z, w1.z);
        WsN[wkk2 * 68 + wc4 + 3] = pack2(w0.w, w1.w);
      }
      if (ks + 32 < chunk) {
        av = ld4(&A[(size_t)(row0 + arow) * K + k0 + ks + 32 + ak4]);
        if (tid < 128) {
          w0 = ld4(&W[(size_t)(k0 + ks + 32 + 2 * wkk2) * 256 + col0 + wc4]);
          w1 = ld4(&W[(size_t)(k0 + ks + 32 + 2 * wkk2 + 1) * 256 + col0 + wc4]);
        }
      }
    }
    __syncthreads();
    cur ^= 1;
  }
  if (bias) {
    float4 b4 = ld4(&bias[col0 + tx * 4]);
#pragma unroll
    for (int i = 0; i < 4; ++i) {
      float4 o;
      o.x = acc[i][0] + b4.x; o.y = acc[i][1] + b4.y;
      o.z = acc[i][2] + b4.z; o.w = acc[i][3] + b4.w;
      st4(&dst[(size_t)(row0 + ty * 4 + i) * 256 + col0 + tx * 4], o);
    }
  } else {
#pragma unroll
    for (int i = 0; i < 4; ++i) {
      float4 o = {acc[i][0], acc[i][1], acc[i][2], acc[i][3]};
      st4(&dst[(size_t)(row0 + ty * 4 + i) * 256 + col0 + tx * 4], o);
    }
  }
}

// ---- transposed-A batched GEMM (upd), f16 LDS, DOUBLE-BUFFERED. batch gb.
// Role split: tid<128 stage A(pred), tid>=128 stage B(nt).
__device__ __forceinline__ void gemmt16(unsigned* ldsU, const float* __restrict__ pred,
                                        const float* __restrict__ nt,
                                        float* __restrict__ pp,
                                        int gb, int n0, int col0, int k0) {
  const int tid = threadIdx.x;
  const int tx = tid & 15, ty = tid >> 4;
  const float* Ab = pred + ((size_t)gb << 16);
  const float* Bb = nt + ((size_t)gb << 16);
  const int t7 = tid & 127;
  const int ee2 = t7 >> 4, cg4 = (t7 & 15) * 4;
  const int base = (tid < 128) ? n0 : col0;
  const float* src = (tid < 128) ? Ab : Bb;
  const int dOff = (tid < 128) ? 0 : 544;
  float acc[4][4] = {{0.f}};
  float4 r0 = ld4(&src[((size_t)(k0 + 2 * ee2) << 8) + base + cg4]);
  float4 r1 = ld4(&src[((size_t)(k0 + 2 * ee2 + 1) << 8) + base + cg4]);
  {
    unsigned* d = ldsU + dOff;
    d[ee2 * 68 + cg4 + 0] = pack2(r0.x, r1.x);
    d[ee2 * 68 + cg4 + 1] = pack2(r0.y, r1.y);
    d[ee2 * 68 + cg4 + 2] = pack2(r0.z, r1.z);
    d[ee2 * 68 + cg4 + 3] = pack2(r0.w, r1.w);
  }
  r0 = ld4(&src[((size_t)(k0 + 16 + 2 * ee2) << 8) + base + cg4]);
  r1 = ld4(&src[((size_t)(k0 + 16 + 2 * ee2 + 1) << 8) + base + cg4]);
  __syncthreads();
  int cur = 0;
  for (int ks = 0; ks < 64; ks += 16) {
    unsigned* AtU = ldsU + cur * 1088;
    unsigned* WsU = AtU + 544;
    DOT_BLOCK(AtU, WsU)
    if (ks + 16 < 64) {
      unsigned* d = ldsU + (cur ^ 1) * 1088 + dOff;
      d[ee2 * 68 + cg4 + 0] = pack2(r0.x, r1.x);
      d[ee2 * 68 + cg4 + 1] = pack2(r0.y, r1.y);
      d[ee2 * 68 + cg4 + 2] = pack2(r0.z, r1.z);
      d[ee2 * 68 + cg4 + 3] = pack2(r0.w, r1.w);
      if (ks + 32 < 64) {
        r0 = ld4(&src[((size_t)(k0 + ks + 32 + 2 * ee2) << 8) + base + cg4]);
        r1 = ld4(&src[((size_t)(k0 + ks + 32 + 2 * ee2 + 1) << 8) + base + cg4]);
      }
    }
    __syncthreads();
    cur ^= 1;
  }
#pragma unroll
  for (int i = 0; i < 4; ++i) {
    float4 o = {acc[i][0], acc[i][1], acc[i][2], acc[i][3]};
    st4(&pp[(((size_t)gb << 8) + n0 + ty * 4 + i) * 256 + col0 + tx * 4], o);
  }
}

// ---- 64x64 GEMM, A = h1 recomputed inline (relu(sum 4 slabs + mt1)), f16 LDS, dbuf.
// ldsU: 2176 uints buffers + 64 floats mt1s at ldsU+2176.
__device__ __forceinline__ void gemm_h116(unsigned* ldsU, const float* __restrict__ part,
                                          const float* __restrict__ mt1p,
                                          const float* __restrict__ W,
                                          float* __restrict__ dst,
                                          int gb, int row0, int col0, int k0) {
  float* mt1s = reinterpret_cast<float*>(ldsU + 2176);  // [64]
  const int tid = threadIdx.x;
  const int tx = tid & 15, ty = tid >> 4;
  const int arow = tid >> 2, ak4 = (tid & 3) * 4;
  const int wkk2 = tid >> 4, wc4 = (tid & 15) * 4;
  if (tid < 64) {
    float s = 0.f;
#pragma unroll
    for (int k2 = 0; k2 < 12; ++k2) s += mt1p[((size_t)(k2 * 4 + gb) << 8) + k0 + tid];
    mt1s[tid] = s;
  }
  float acc[4][4] = {{0.f}};
  size_t ao = (size_t)(row0 + arow) * 256 + k0 + ak4;
  float4 p0 = ld4(&part[ao]);
  float4 p1 = ld4(&part[ao + 262144]);
  float4 p2 = ld4(&part[ao + 524288]);
  float4 p3 = ld4(&part[ao + 786432]);
  float4 w0, w1;
  if (tid < 128) {
    w0 = ld4(&W[(size_t)(k0 + 2 * wkk2) * 256 + col0 + wc4]);
    w1 = ld4(&W[(size_t)(k0 + 2 * wkk2 + 1) * 256 + col0 + wc4]);
  }
  __syncthreads();  // mt1s visible
  {
    float4 m = ld4(&mt1s[ak4]);
    float ax = fmaxf(p0.x + p1.x + p2.x + p3.x + m.x, 0.f);
    float ay = fmaxf(p0.y + p1.y + p2.y + p3.y + m.y, 0.f);
    float az = fmaxf(p0.z + p1.z + p2.z + p3.z + m.z, 0.f);
    float aw = fmaxf(p0.w + p1.w + p2.w + p3.w + m.w, 0.f);
    ldsU[(ak4 >> 1) * 68 + arow] = pack2(ax, ay);
    ldsU[((ak4 >> 1) + 1) * 68 + arow] = pack2(az, aw);
    if (tid < 128) {
      unsigned* WsU = ldsU + 544;
      WsU[wkk2 * 68 + wc4 + 0] = pack2(w0.x, w1.x);
      WsU[wkk2 * 68 + wc4 + 1] = pack2(w0.y, w1.y);
      WsU[wkk2 * 68 + wc4 + 2] = pack2(w0.z, w1.z);
      WsU[wkk2 * 68 + wc4 + 3] = pack2(w0.w, w1.w);
    }
  }
  {
    size_t an = (size_t)(row0 + arow) * 256 + k0 + 16 + ak4;
    p0 = ld4(&part[an]);
    p1 = ld4(&part[an + 262144]);
    p2 = ld4(&part[an + 524288]);
    p3 = ld4(&part[an + 786432]);
    if (tid < 128) {
      w0 = ld4(&W[(size_t)(k0 + 16 + 2 * wkk2) * 256 + col0 + wc4]);
      w1 = ld4(&W[(size_t)(k0 + 16 + 2 * wkk2 + 1) * 256 + col0 + wc4]);
    }
  }
  __syncthreads();
  int cur = 0;
  for (int ks = 0; ks < 64; ks += 16) {
    unsigned* AtU = ldsU + cur * 1088;
    unsigned* WsU = AtU + 544;
    DOT_BLOCK(AtU, WsU)
    if (ks + 16 < 64) {
      unsigned* AtN = ldsU + (cur ^ 1) * 1088;
      unsigned* WsN = AtN + 544;
      float4 m = ld4(&mt1s[ks + 16 + ak4]);
      float ax = fmaxf(p0.x + p1.x + p2.x + p3.x + m.x, 0.f);
      float ay = fmaxf(p0.y + p1.y + p2.y + p3.y + m.y, 0.f);
      float az = fmaxf(p0.z + p1.z + p2.z + p3.z + m.z, 0.f);
      float aw = fmaxf(p0.w + p1.w + p2.w + p3.w + m.w, 0.f);
      AtN[(ak4 >> 1) * 68 + arow] = pack2(ax, ay);
      AtN[((ak4 >> 1) + 1) * 68 + arow] = pack2(az, aw);
      if (tid < 128) {
        WsN[wkk2 * 68 + wc4 + 0] = pack2(w0.x, w1.x);
        WsN[wkk2 * 68 + wc4 + 1] = pack2(w0.y, w1.y);
        WsN[wkk2 * 68 + wc4 + 2] = pack2(w0.z, w1.z);
        WsN[wkk2 * 68 + wc4 + 3] = pack2(w0.w, w1.w);
      }
      if (ks + 32 < 64) {
        size_t an = (size_t)(row0 + arow) * 256 + k0 + ks + 32 + ak4;
        p0 = ld4(&part[an]);
        p1 = ld4(&part[an + 262144]);
        p2 = ld4(&part[an + 524288]);
        p3 = ld4(&part[an + 786432]);
        if (tid < 128) {
          w0 = ld4(&W[(size_t)(k0 + ks + 32 + 2 * wkk2) * 256 + col0 + wc4]);
          w1 = ld4(&W[(size_t)(k0 + ks + 32 + 2 * wkk2 + 1) * 256 + col0 + wc4]);
        }
      }
    }
    __syncthreads();
    cur ^= 1;
  }
#pragma unroll
  for (int i = 0; i < 4; ++i) {
    float4 o = {acc[i][0], acc[i][1], acc[i][2], acc[i][3]};
    st4(&dst[(size_t)(row0 + ty * 4 + i) * 256 + col0 + tx * 4], o);
  }
}

__device__ __forceinline__ void wred2(float& s, float& q) {
#pragma unroll
  for (int off = 32; off; off >>= 1) {
    s += __shfl_xor(s, off);
    q += __shfl_xor(q, off);
  }
}

// ---- colmean(64-col slice of X) + mean-linear partial (f32).
__device__ __forceinline__ void mtk_dev(float* lds, const float* __restrict__ X,
                                        const float* __restrict__ Wl,
                                        const float* __restrict__ bias,
                                        float* __restrict__ mtp, int gb, int ks, int Kd) {
  float* sm = lds;
  float* m64 = lds + 256;
  const int tid = threadIdx.x;
  const int col = tid & 63, q = tid >> 6;
  const float* xb = X + (size_t)(gb * 256 + q * 64) * Kd + ks * 64 + col;
  float s = 0.f;
#pragma unroll 8
  for (int r = 0; r < 64; ++r) s += xb[(size_t)r * Kd];
  sm[tid] = s;
  __syncthreads();
  if (tid < 64) m64[tid] = (sm[tid] + sm[tid + 64] + sm[tid + 128] + sm[tid + 192]) * (1.f / 256.f);
  __syncthreads();
  const int c = tid;
  float acc = (ks == 0) ? bias[c] : 0.f;
  const float* wp = Wl + (size_t)ks * 64 * 256 + c;
#pragma unroll 8
  for (int k = 0; k < 64; ++k) acc = fmaf(m64[k], wp[(size_t)k * 256], acc);
  mtp[((size_t)(ks * 4 + gb) << 8) + c] = acc;
}

// ---- colmean of h1 (recomputed inline: relu(sum part slabs + mt1)) + W2l partial (f32).
__device__ __forceinline__ void mtk_h1(float* lds, const float* __restrict__ part,
                                       const float* __restrict__ mt1p,
                                       const float* __restrict__ Wl,
                                       const float* __restrict__ bias,
                                       float* __restrict__ mtp, int gb, int ks) {
  float* sm = lds;
  float* m64 = lds + 256;
  const int tid = threadIdx.x;
  const int col = tid & 63, q = tid >> 6;
  float mt1v = 0.f;
#pragma unroll
  for (int k2 = 0; k2 < 12; ++k2) mt1v += mt1p[((size_t)(k2 * 4 + gb) << 8) + ks * 64 + col];
  const float* pb = part + (size_t)(gb * 256 + q * 64) * 256 + ks * 64 + col;
  float s = 0.f;
#pragma unroll 4
  for (int r = 0; r < 64; ++r) {
    size_t o = (size_t)r * 256;
    float v = pb[o] + pb[o + 262144] + pb[o + 524288] + pb[o + 786432] + mt1v;
    s += fmaxf(v, 0.f);
  }
  sm[tid] = s;
  __syncthreads();
  if (tid < 64) m64[tid] = (sm[tid] + sm[tid + 64] + sm[tid + 128] + sm[tid + 192]) * (1.f / 256.f);
  __syncthreads();
  const int c = tid;
  float acc = (ks == 0) ? bias[c] : 0.f;
  const float* wp = Wl + (size_t)ks * 64 * 256 + c;
#pragma unroll 8
  for (int k = 0; k < 64; ++k) acc = fmaf(m64[k], wp[(size_t)k * 256], acc);
  mtp[((size_t)(ks * 4 + gb) << 8) + c] = acc;
}

// ================== kernels ==================

// gemm: grid (16 mtiles, 4 ntiles, KS), block 256.
__global__ __launch_bounds__(256) void k_gemm(const float* __restrict__ A,
                                              const float* __restrict__ W,
                                              const float* __restrict__ bias,
                                              float* __restrict__ dst,
                                              int K, int chunk) {
  __shared__ unsigned ldsU[2176];
  float* base = bias ? dst : dst + (size_t)blockIdx.z * 262144;
  gemm16(ldsU, A, W, bias, base, K, chunk,
         blockIdx.x * 64, blockIdx.y * 64, blockIdx.z * chunk);
}

// merged P0+P1 for iter 0: grid 320 1-D. b<256: xp partials (v_t@Wx). b>=256: x_in.
__global__ __launch_bounds__(256) void k_gemm0(const float* __restrict__ v_t,
                                               const float* __restrict__ Wx,
                                               float* __restrict__ part,
                                               const float* __restrict__ inputs,
                                               const float* __restrict__ Wp,
                                               const float* __restrict__ bp,
                                               float* __restrict__ x_in) {
  __shared__ unsigned ldsU[2176];
  const int b = blockIdx.x;
  if (b < 256) {
    int mt = b & 15, ntile = (b >> 4) & 3, kz = b >> 6;
    gemm16(ldsU, v_t, Wx, nullptr, part + (size_t)kz * 262144, 256, 64,
           mt * 64, ntile * 64, kz * 64);
  } else {
    int idx = b - 256;  // 0..63
    int mt = idx & 15, ntile = idx >> 4;
    gemm16(ldsU, inputs, Wp, bp, x_in, 128, 128, mt * 64, ntile * 64, 0);
  }
}

// fused adjacency (f32, verified): grid (8, 8, 4), block 256.
__global__ __launch_bounds__(256) void k_adj(const float* __restrict__ part,
                                             const float* __restrict__ incold,
                                             const float* __restrict__ wi,
                                             const float* __restrict__ bi,
                                             const float* __restrict__ bx,
                                             const float* __restrict__ wsv,
                                             const float* __restrict__ bs,
                                             float* __restrict__ pred,
                                             float* __restrict__ pred2) {
  __shared__ float lds[8448];
  float* tn = lds;
  float* te = lds + 32 * 132;
  const int n0 = blockIdx.x * 32, e0 = blockIdx.y * 32, gb = blockIdx.z;
  const int tid = threadIdx.x;
  const size_t rb = (size_t)gb * 256;
  const int tx = tid & 15, ty = tid >> 4;
  float incv[2][2], acc[2][2];
#pragma unroll
  for (int j = 0; j < 2; ++j)
#pragma unroll
    for (int i = 0; i < 2; ++i) {
      incv[j][i] = incold[((rb + e0 + ty + 16 * j) << 8) + n0 + tx + 16 * i];
      acc[j][i] = 0.f;
    }
  for (int dh = 0; dh < 256; dh += 128) {
    if (dh) __syncthreads();
#pragma unroll
    for (int s = 0; s < 4; ++s) {
      int idx = tid + s * 256;
      int row = idx >> 5;
      int d = dh + (idx & 31) * 4;
      float4 bxv = ld4(&bx[d]);
      {
        size_t o = ((rb + n0 + row) << 8) + d;
        float4 p0 = ld4(&part[o]);
        float4 p1 = ld4(&part[o + 262144]);
        float4 p2 = ld4(&part[o + 524288]);
        float4 p3 = ld4(&part[o + 786432]);
        float4 v;
        v.x = p0.x + p1.x + p2.x + p3.x + bxv.x;
        v.y = p0.y + p1.y + p2.y + p3.y + bxv.y;
        v.z = p0.z + p1.z + p2.z + p3.z + bxv.z;
        v.w = p0.w + p1.w + p2.w + p3.w + bxv.w;
        st4(&tn[row * 132 + (d - dh)], v);
      }
      {
        size_t o = ((rb + e0 + row) << 8) + d;
        float4 p0 = ld4(&part[o]);
        float4 p1 = ld4(&part[o + 262144]);
        float4 p2 = ld4(&part[o + 524288]);
        float4 p3 = ld4(&part[o + 786432]);
        float4 bv = ld4(&bi[d]);
        float4 v;
        v.x = p0.x + p1.x + p2.x + p3.x + bxv.x + bv.x;
        v.y = p0.y + p1.y + p2.y + p3.y + bxv.y + bv.y;
        v.z = p0.z + p1.z + p2.z + p3.z + bxv.z + bv.z;
        v.w = p0.w + p1.w + p2.w + p3.w + bxv.w + bv.w;
        st4(&te[row * 132 + (d - dh)], v);
      }
    }
    __syncthreads();
#pragma unroll 4
    for (int dl = 0; dl < 128; dl += 4) {
      float4 wiq = ld4(&wi[dh + dl]);
      float4 wsq = ld4(&wsv[dh + dl]);
      float4 xn0 = ld4(&tn[tx * 132 + dl]);
      float4 xn1 = ld4(&tn[(tx + 16) * 132 + dl]);
      float4 xe0 = ld4(&te[ty * 132 + dl]);
      float4 xe1 = ld4(&te[(ty + 16) * 132 + dl]);
#pragma unroll
      for (int j = 0; j < 2; ++j) {
        float4 xe = j ? xe1 : xe0;
#pragma unroll
        for (int i = 0; i < 2; ++i) {
          float4 xn = i ? xn1 : xn0;
          float u;
          u = fmaf(incv[j][i], wiq.x, xn.x + xe.x); u = fmaxf(u, 0.f); acc[j][i] = fmaf(u, wsq.x, acc[j][i]);
          u = fmaf(incv[j][i], wiq.y, xn.y + xe.y); u = fmaxf(u, 0.f); acc[j][i] = fmaf(u, wsq.y, acc[j][i]);
          u = fmaf(incv[j][i], wiq.z, xn.z + xe.z); u = fmaxf(u, 0.f); acc[j][i] = fmaf(u, wsq.z, acc[j][i]);
          u = fmaf(incv[j][i], wiq.w, xn.w + xe.w); u = fmaxf(u, 0.f); acc[j][i] = fmaf(u, wsq.w, acc[j][i]);
        }
      }
    }
  }
  const float b0 = bs[0];
#pragma unroll
  for (int j = 0; j < 2; ++j)
#pragma unroll
    for (int i = 0; i < 2; ++i) {
      float s = acc[j][i] + b0;
      float v = 1.f / (1.f + __expf(-s));
      size_t o = ((rb + e0 + ty + 16 * j) << 8) + n0 + tx + 16 * i;
      pred[o] = v;
      if (pred2) pred2[o] = v;
    }
}

// transposed-A GEMM: grid (4 ntiles, 4 ctiles, 16 = gb*4+kc), block 256.
__global__ __launch_bounds__(256) void k_gemmt(const float* __restrict__ pred,
                                               const float* __restrict__ nt,
                                               float* __restrict__ part) {
  __shared__ unsigned ldsU[2176];
  const int gb = blockIdx.z >> 2, kc = blockIdx.z & 3;
  gemmt16(ldsU, pred, nt, part + (size_t)kc * 262144,
          gb, blockIdx.x * 64, blockIdx.y * 64, kc * 64);
}

// reduce upd partials + LN(concat) -> h. grid 256, block 256.
__global__ __launch_bounds__(256) void k_ln768(const float* __restrict__ part,
                                               const float* __restrict__ x_in,
                                               const float* __restrict__ nt,
                                               const float* __restrict__ g,
                                               const float* __restrict__ be,
                                               float* __restrict__ h) {
  const int row = blockIdx.x * 4 + (threadIdx.x >> 6);
  const int lane = threadIdx.x & 63;
  const int c4 = lane * 4;
  const size_t ro = (size_t)row * 256 + c4;
  float4 u = ld4(&part[ro]);
  float4 u1 = ld4(&part[ro + 262144]);
  float4 u2 = ld4(&part[ro + 524288]);
  float4 u3 = ld4(&part[ro + 786432]);
  u.x += u1.x + u2.x + u3.x;
  u.y += u1.y + u2.y + u3.y;
  u.z += u1.z + u2.z + u3.z;
  u.w += u1.w + u2.w + u3.w;
  float4 xi = ld4(&x_in[ro]);
  float4 nv = ld4(&nt[ro]);
  float s = xi.x + xi.y + xi.z + xi.w + nv.x + nv.y + nv.z + nv.w + u.x + u.y + u.z + u.w;
  float sq = xi.x * xi.x + xi.y * xi.y + xi.z * xi.z + xi.w * xi.w
           + nv.x * nv.x + nv.y * nv.y + nv.z * nv.z + nv.w * nv.w
           + u.x * u.x + u.y * u.y + u.z * u.z + u.w * u.w;
  wred2(s, sq);
  float mu = s * (1.f / 768.f);
  float rs = rsqrtf(sq * (1.f / 768.f) - mu * mu + LN_EPS);
  float* hr = h + (size_t)row * 768;
  {
    float4 g4 = ld4(&g[c4]), b4 = ld4(&be[c4]), o;
    o.x = (xi.x - mu) * rs * g4.x + b4.x;
    o.y = (xi.y - mu) * rs * g4.y + b4.y;
    o.z = (xi.z - mu) * rs * g4.z + b4.z;
    o.w = (xi.w - mu) * rs * g4.w + b4.w;
    st4(&hr[c4], o);
  }
  {
    float4 g4 = ld4(&g[256 + c4]), b4 = ld4(&be[256 + c4]), o;
    o.x = (nv.x - mu) * rs * g4.x + b4.x;
    o.y = (nv.y - mu) * rs * g4.y + b4.y;
    o.z = (nv.z - mu) * rs * g4.z + b4.z;
    o.w = (nv.w - mu) * rs * g4.w + b4.w;
    st4(&hr[256 + c4], o);
  }
  {
    float4 g4 = ld4(&g[512 + c4]), b4 = ld4(&be[512 + c4]), o;
    o.x = (u.x - mu) * rs * g4.x + b4.x;
    o.y = (u.y - mu) * rs * g4.y + b4.y;
    o.z = (u.z - mu) * rs * g4.z + b4.z;
    o.w = (u.w - mu) * rs * g4.w + b4.w;
    st4(&hr[512 + c4], o);
  }
}

// gemm768 (h @ W1g -> part) + mt1 partials, 1-D grid 304, block 256.
__global__ __launch_bounds__(256) void k_g768mtk(const float* __restrict__ h,
                                                 const float* __restrict__ W1g,
                                                 const float* __restrict__ W1l,
                                                 const float* __restrict__ b1,
                                                 float* __restrict__ part,
                                                 float* __restrict__ mt1p) {
  __shared__ unsigned ldsU[2176];
  const int b = blockIdx.x;
  if (b < 256) {
    int mt = b & 15, ntile = (b >> 4) & 3, kz = b >> 6;
    gemm16(ldsU, h, W1g, nullptr, part + (size_t)kz * 262144, 768, 192,
           mt * 64, ntile * 64, kz * 192);
  } else {
    int idx = b - 256;           // 0..47
    mtk_dev(reinterpret_cast<float*>(ldsU), h, W1l, b1, mt1p, idx & 3, idx >> 2, 768);
  }
}

// gemm_h1 (relu(h1) @ W2g -> part2) + mt2 partials, 1-D grid 272, block 256.
__global__ __launch_bounds__(256) void k_gh1mtk2(const float* __restrict__ part,
                                                 const float* __restrict__ mt1p,
                                                 const float* __restrict__ W2g,
                                                 const float* __restrict__ W2l,
                                                 const float* __restrict__ b2,
                                                 float* __restrict__ part2,
                                                 float* __restrict__ mt2p) {
  __shared__ unsigned ldsU[2240];
  const int b = blockIdx.x;
  if (b < 256) {
    int mt = b & 15, ntile = (b >> 4) & 3, kz = b >> 6;
    gemm_h116(ldsU, part, mt1p, W2g, part2 + (size_t)kz * 262144,
              mt >> 2, mt * 64, ntile * 64, kz * 64);
  } else {
    int idx = b - 256;           // 0..15
    mtk_h1(reinterpret_cast<float*>(ldsU), part, mt1p, W2l, b2, mt2p, idx & 3, idx >> 2);
  }
}

// reduce part2 partials + mt2 + residual + LN -> dst. grid 256, block 256.
__global__ __launch_bounds__(256) void k_ln256(const float* __restrict__ part2,
                                               const float* __restrict__ nt,
                                               const float* __restrict__ mt2p,
                                               const float* __restrict__ g,
                                               const float* __restrict__ be,
                                               float* __restrict__ dst) {
  const int row = blockIdx.x * 4 + (threadIdx.x >> 6);
  const int lane = threadIdx.x & 63;
  const int c4 = lane * 4;
  const int gb = row >> 8;
  const size_t ro = (size_t)row * 256 + c4;
  float4 p0 = ld4(&part2[ro]);
  float4 p1 = ld4(&part2[ro + 262144]);
  float4 p2 = ld4(&part2[ro + 524288]);
  float4 p3 = ld4(&part2[ro + 786432]);
  float4 m4 = {0.f, 0.f, 0.f, 0.f};
#pragma unroll
  for (int k2 = 0; k2 < 4; ++k2) {
    float4 mv = ld4(&mt2p[((size_t)(k2 * 4 + gb) << 8) + c4]);
    m4.x += mv.x; m4.y += mv.y; m4.z += mv.z; m4.w += mv.w;
  }
  float4 nv = ld4(&nt[ro]);
  float4 x;
  x.x = nv.x + p0.x + p1.x + p2.x + p3.x + m4.x;
  x.y = nv.y + p0.y + p1.y + p2.y + p3.y + m4.y;
  x.z = nv.z + p0.z + p1.z + p2.z + p3.z + m4.z;
  x.w = nv.w + p0.w + p1.w + p2.w + p3.w + m4.w;
  float s = x.x + x.y + x.z + x.w;
  float sq = x.x * x.x + x.y * x.y + x.z * x.z + x.w * x.w;
  wred2(s, sq);
  float mu = s * (1.f / 256.f);
  float rs = rsqrtf(sq * (1.f / 256.f) - mu * mu + LN_EPS);
  float4 g4 = ld4(&g[c4]), b4 = ld4(&be[c4]), o;
  o.x = (x.x - mu) * rs * g4.x + b4.x;
  o.y = (x.y - mu) * rs * g4.y + b4.y;
  o.z = (x.z - mu) * rs * g4.z + b4.z;
  o.w = (x.w - mu) * rs * g4.w + b4.w;
  st4(&dst[ro], o);
}

extern "C" void kernel_launch(void* const* d_in, const int* in_sizes, int n_in,
                              void* d_out, int out_size, void* d_ws, size_t ws_size,
                              hipStream_t stream) {
  (void)in_sizes; (void)n_in; (void)out_size; (void)ws_size;
  const float* inputs = (const float*)d_in[0];
  const float* v_t    = (const float*)d_in[1];
  const float* i_t    = (const float*)d_in[2];
  const float* Wp     = (const float*)d_in[3];
  const float* bp     = (const float*)d_in[4];
  const float* Wx     = (const float*)d_in[5];
  const float* bx     = (const float*)d_in[6];
  const float* wi     = (const float*)d_in[7];
  const float* bi     = (const float*)d_in[8];
  const float* ws     = (const float*)d_in[9];
  const float* bs     = (const float*)d_in[10];
  const float* g_pre  = (const float*)d_in[11];
  const float* be_pre = (const float*)d_in[12];
  const float* g_n    = (const float*)d_in[13];
  const float* be_n   = (const float*)d_in[14];
  const float* W1g    = (const float*)d_in[15];
  const float* W1l    = (const float*)d_in[16];
  const float* b1     = (const float*)d_in[17];
  const float* W2g    = (const float*)d_in[18];
  const float* W2l    = (const float*)d_in[19];
  const float* b2     = (const float*)d_in[20];
  float* out = (float*)d_out;
  float* wsf = (float*)d_ws;
  float* x_in  = wsf;                  // 1 MB
  float* ntA   = wsf + 262144;         // 1 MB
  float* ntB   = wsf + 524288;         // 1 MB
  float* h     = wsf + 786432;         // 3 MB (dead after k_g768mtk)
  float* part2 = wsf + 786432;         // 4 MB = h + old-h1 region
  float* part  = wsf + 1835008;        // 4 MB
  float* mt1p  = wsf + 2883584;        // 48 KB
  float* mt2p  = wsf + 2895872;        // 16 KB

  for (int t = 0; t < 3; ++t) {
    const float* ntCur = (t == 0) ? v_t : ((t == 1) ? ntA : ntB);
    float* dstNt = (t == 2) ? (out + 786432) : ((t == 0) ? ntA : ntB);
    const float* incold = (t == 0) ? i_t : (out + (size_t)(t - 1) * 262144);
    float* pred = out + (size_t)t * 262144;
    float* pred2 = (t == 2) ? (out + 1048576) : nullptr;

    // P1: xp partials = ntCur @ Wx (K-split 4); at t=0 also x_in as extra blocks
    if (t == 0) {
      k_gemm0<<<320, 256, 0, stream>>>(v_t, Wx, part, inputs, Wp, bp, x_in);
    } else {
      k_gemm<<<dim3(16, 4, 4), 256, 0, stream>>>(ntCur, Wx, nullptr, part, 256, 64);
    }
    // P2: inc = sigmoid(sum_d relu(xp[n]+xp[e]+bi + inc*wi) * ws + bs)
    k_adj<<<dim3(8, 8, 4), 256, 0, stream>>>(part, incold, wi, bi, bx, ws, bs, pred, pred2);
    // P3: upd partials = pred^T @ ntCur (e-split 4)
    k_gemmt<<<dim3(4, 4, 16), 256, 0, stream>>>(pred, ntCur, part);
    // P4: h = LN(concat(x_in, nt, upd))
    k_ln768<<<256, 256, 0, stream>>>(part, x_in, ntCur, g_pre, be_pre, h);
    // P5: gemm768 partials + mt1 partials (one dispatch)
    k_g768mtk<<<304, 256, 0, stream>>>(h, W1g, W1l, b1, part, mt1p);
    // P6: part2 partials = relu(h1 inline) @ W2g + mt2 partials (one dispatch)
    k_gh1mtk2<<<272, 256, 0, stream>>>(part, mt1p, W2g, W2l, b2, part2, mt2p);
    // P7: nt' = LN(nt + sum part2 + mt2)
    k_ln256<<<256, 256, 0, stream>>>(part2, ntCur, mt2p, g_n, be_n, dstNt);
  }
}

// Round 10
// 193.572 us; speedup vs baseline: 1.0178x; 1.0178x over previous
//
#include <hip/hip_runtime.h>
#include <cstddef>

#define LN_EPS 1e-5f

__device__ inline float4 ld4(const float* p) { return *reinterpret_cast<const float4*>(p); }
__device__ inline void st4(float* p, float4 v) { *reinterpret_cast<float4*>(p) = v; }

typedef _Float16 h2_t __attribute__((ext_vector_type(2)));

__device__ __forceinline__ unsigned pack2(float x, float y) {
  h2_t h;
  h.x = (_Float16)x;
  h.y = (_Float16)y;
  return __builtin_bit_cast(unsigned, h);
}

// dot2: c += a.x*b.x + a.y*b.y  (f16 inputs, f32 accumulate)
__device__ __forceinline__ float dot2(unsigned a, unsigned b, float c) {
  h2_t ah = __builtin_bit_cast(h2_t, a);
  h2_t bh = __builtin_bit_cast(h2_t, b);
#if __has_builtin(__builtin_amdgcn_fdot2)
  return __builtin_amdgcn_fdot2(ah, bh, c, false);
#else
  return fmaf((float)ah.x, (float)bh.x, fmaf((float)ah.y, (float)bh.y, c));
#endif
}

// ---- 64x64 tile GEMM, f16 LDS (k-pair packed), 4x4 micro, KSTEP 16, pipelined.
// LDS: AtU [8 kk2][68] (pairs x rows), WsU [8 kk2][68] (pairs x cols). 1088 uints.
// A role: all 256 threads (1 row x 4 k). W role: tid<128 (1 pair-row x 4 cols).
__device__ __forceinline__ void gemm16(unsigned* ldsU, const float* __restrict__ A,
                                       const float* __restrict__ W,
                                       const float* __restrict__ bias,
                                       float* __restrict__ dst,
                                       int K, int chunk, int row0, int col0, int k0) {
  unsigned* AtU = ldsU;
  unsigned* WsU = ldsU + 544;
  const int tid = threadIdx.x;
  const int tx = tid & 15, ty = tid >> 4;
  const int arow = tid >> 2, ak4 = (tid & 3) * 4;
  const int wkk2 = tid >> 4, wc4 = (tid & 15) * 4;  // valid when tid<128
  float acc[4][4] = {{0.f}};
  float4 av = ld4(&A[(size_t)(row0 + arow) * K + k0 + ak4]);
  float4 w0, w1;
  if (tid < 128) {
    w0 = ld4(&W[(size_t)(k0 + 2 * wkk2) * 256 + col0 + wc4]);
    w1 = ld4(&W[(size_t)(k0 + 2 * wkk2 + 1) * 256 + col0 + wc4]);
  }
  for (int ks = 0; ks < chunk; ks += 16) {
    __syncthreads();
    AtU[(ak4 >> 1) * 68 + arow] = pack2(av.x, av.y);
    AtU[((ak4 >> 1) + 1) * 68 + arow] = pack2(av.z, av.w);
    if (tid < 128) {
      WsU[wkk2 * 68 + wc4 + 0] = pack2(w0.x, w1.x);
      WsU[wkk2 * 68 + wc4 + 1] = pack2(w0.y, w1.y);
      WsU[wkk2 * 68 + wc4 + 2] = pack2(w0.z, w1.z);
      WsU[wkk2 * 68 + wc4 + 3] = pack2(w0.w, w1.w);
    }
    __syncthreads();
    if (ks + 16 < chunk) {
      av = ld4(&A[(size_t)(row0 + arow) * K + k0 + ks + 16 + ak4]);
      if (tid < 128) {
        w0 = ld4(&W[(size_t)(k0 + ks + 16 + 2 * wkk2) * 256 + col0 + wc4]);
        w1 = ld4(&W[(size_t)(k0 + ks + 16 + 2 * wkk2 + 1) * 256 + col0 + wc4]);
      }
    }
#pragma unroll
    for (int kk2 = 0; kk2 < 8; ++kk2) {
      uint4 a4 = *reinterpret_cast<const uint4*>(&AtU[kk2 * 68 + ty * 4]);
      uint4 w4 = *reinterpret_cast<const uint4*>(&WsU[kk2 * 68 + tx * 4]);
      acc[0][0] = dot2(a4.x, w4.x, acc[0][0]); acc[0][1] = dot2(a4.x, w4.y, acc[0][1]);
      acc[0][2] = dot2(a4.x, w4.z, acc[0][2]); acc[0][3] = dot2(a4.x, w4.w, acc[0][3]);
      acc[1][0] = dot2(a4.y, w4.x, acc[1][0]); acc[1][1] = dot2(a4.y, w4.y, acc[1][1]);
      acc[1][2] = dot2(a4.y, w4.z, acc[1][2]); acc[1][3] = dot2(a4.y, w4.w, acc[1][3]);
      acc[2][0] = dot2(a4.z, w4.x, acc[2][0]); acc[2][1] = dot2(a4.z, w4.y, acc[2][1]);
      acc[2][2] = dot2(a4.z, w4.z, acc[2][2]); acc[2][3] = dot2(a4.z, w4.w, acc[2][3]);
      acc[3][0] = dot2(a4.w, w4.x, acc[3][0]); acc[3][1] = dot2(a4.w, w4.y, acc[3][1]);
      acc[3][2] = dot2(a4.w, w4.z, acc[3][2]); acc[3][3] = dot2(a4.w, w4.w, acc[3][3]);
    }
  }
  if (bias) {
    float4 b4 = ld4(&bias[col0 + tx * 4]);
#pragma unroll
    for (int i = 0; i < 4; ++i) {
      float4 o;
      o.x = acc[i][0] + b4.x; o.y = acc[i][1] + b4.y;
      o.z = acc[i][2] + b4.z; o.w = acc[i][3] + b4.w;
      st4(&dst[(size_t)(row0 + ty * 4 + i) * 256 + col0 + tx * 4], o);
    }
  } else {
#pragma unroll
    for (int i = 0; i < 4; ++i) {
      float4 o = {acc[i][0], acc[i][1], acc[i][2], acc[i][3]};
      st4(&dst[(size_t)(row0 + ty * 4 + i) * 256 + col0 + tx * 4], o);
    }
  }
}

// ---- transposed-A batched GEMM (upd), f16 LDS, pairs along e. batch gb.
// Role split: tid<128 stage A(pred), tid>=128 stage B(nt); each 1 pair-row x 4 cols.
__device__ __forceinline__ void gemmt16(unsigned* ldsU, const float* __restrict__ pred,
                                        const float* __restrict__ nt,
                                        float* __restrict__ pp,
                                        int gb, int n0, int col0, int k0) {
  unsigned* AtU = ldsU;
  unsigned* WsU = ldsU + 544;
  const int tid = threadIdx.x;
  const int tx = tid & 15, ty = tid >> 4;
  const float* Ab = pred + ((size_t)gb << 16);
  const float* Bb = nt + ((size_t)gb << 16);
  const int t7 = tid & 127;
  const int ee2 = t7 >> 4, cg4 = (t7 & 15) * 4;
  const int base = (tid < 128) ? n0 : col0;
  const float* src = (tid < 128) ? Ab : Bb;
  unsigned* dstU = (tid < 128) ? AtU : WsU;
  float acc[4][4] = {{0.f}};
  float4 r0 = ld4(&src[((size_t)(k0 + 2 * ee2) << 8) + base + cg4]);
  float4 r1 = ld4(&src[((size_t)(k0 + 2 * ee2 + 1) << 8) + base + cg4]);
  for (int ks = 0; ks < 64; ks += 16) {
    __syncthreads();
    dstU[ee2 * 68 + cg4 + 0] = pack2(r0.x, r1.x);
    dstU[ee2 * 68 + cg4 + 1] = pack2(r0.y, r1.y);
    dstU[ee2 * 68 + cg4 + 2] = pack2(r0.z, r1.z);
    dstU[ee2 * 68 + cg4 + 3] = pack2(r0.w, r1.w);
    __syncthreads();
    if (ks + 16 < 64) {
      r0 = ld4(&src[((size_t)(k0 + ks + 16 + 2 * ee2) << 8) + base + cg4]);
      r1 = ld4(&src[((size_t)(k0 + ks + 16 + 2 * ee2 + 1) << 8) + base + cg4]);
    }
#pragma unroll
    for (int kk2 = 0; kk2 < 8; ++kk2) {
      uint4 a4 = *reinterpret_cast<const uint4*>(&AtU[kk2 * 68 + ty * 4]);
      uint4 w4 = *reinterpret_cast<const uint4*>(&WsU[kk2 * 68 + tx * 4]);
      acc[0][0] = dot2(a4.x, w4.x, acc[0][0]); acc[0][1] = dot2(a4.x, w4.y, acc[0][1]);
      acc[0][2] = dot2(a4.x, w4.z, acc[0][2]); acc[0][3] = dot2(a4.x, w4.w, acc[0][3]);
      acc[1][0] = dot2(a4.y, w4.x, acc[1][0]); acc[1][1] = dot2(a4.y, w4.y, acc[1][1]);
      acc[1][2] = dot2(a4.y, w4.z, acc[1][2]); acc[1][3] = dot2(a4.y, w4.w, acc[1][3]);
      acc[2][0] = dot2(a4.z, w4.x, acc[2][0]); acc[2][1] = dot2(a4.z, w4.y, acc[2][1]);
      acc[2][2] = dot2(a4.z, w4.z, acc[2][2]); acc[2][3] = dot2(a4.z, w4.w, acc[2][3]);
      acc[3][0] = dot2(a4.w, w4.x, acc[3][0]); acc[3][1] = dot2(a4.w, w4.y, acc[3][1]);
      acc[3][2] = dot2(a4.w, w4.z, acc[3][2]); acc[3][3] = dot2(a4.w, w4.w, acc[3][3]);
    }
  }
#pragma unroll
  for (int i = 0; i < 4; ++i) {
    float4 o = {acc[i][0], acc[i][1], acc[i][2], acc[i][3]};
    st4(&pp[(((size_t)gb << 8) + n0 + ty * 4 + i) * 256 + col0 + tx * 4], o);
  }
}

// ---- 64x64 GEMM, A = h1 recomputed inline: relu(sum_4 part slabs + mt1), f16 LDS.
__device__ __forceinline__ void gemm_h116(unsigned* ldsU, const float* __restrict__ part,
                                          const float* __restrict__ mt1p,
                                          const float* __restrict__ W,
                                          float* __restrict__ dst,
                                          int gb, int row0, int col0, int k0) {
  unsigned* AtU = ldsU;
  unsigned* WsU = ldsU + 544;
  float* mt1s = reinterpret_cast<float*>(ldsU + 1088);  // [64]
  const int tid = threadIdx.x;
  const int tx = tid & 15, ty = tid >> 4;
  const int arow = tid >> 2, ak4 = (tid & 3) * 4;
  const int wkk2 = tid >> 4, wc4 = (tid & 15) * 4;
  if (tid < 64) {
    float s = 0.f;
#pragma unroll
    for (int k2 = 0; k2 < 12; ++k2) s += mt1p[((size_t)(k2 * 4 + gb) << 8) + k0 + tid];
    mt1s[tid] = s;
  }
  float acc[4][4] = {{0.f}};
  size_t ao = (size_t)(row0 + arow) * 256 + k0 + ak4;
  float4 p0 = ld4(&part[ao]);
  float4 p1 = ld4(&part[ao + 262144]);
  float4 p2 = ld4(&part[ao + 524288]);
  float4 p3 = ld4(&part[ao + 786432]);
  float4 w0, w1;
  if (tid < 128) {
    w0 = ld4(&W[(size_t)(k0 + 2 * wkk2) * 256 + col0 + wc4]);
    w1 = ld4(&W[(size_t)(k0 + 2 * wkk2 + 1) * 256 + col0 + wc4]);
  }
  for (int ks = 0; ks < 64; ks += 16) {
    __syncthreads();   // also makes mt1s visible on first pass
    float4 m = ld4(&mt1s[ks + ak4]);
    float ax = fmaxf(p0.x + p1.x + p2.x + p3.x + m.x, 0.f);
    float ay = fmaxf(p0.y + p1.y + p2.y + p3.y + m.y, 0.f);
    float az = fmaxf(p0.z + p1.z + p2.z + p3.z + m.z, 0.f);
    float aw = fmaxf(p0.w + p1.w + p2.w + p3.w + m.w, 0.f);
    AtU[(ak4 >> 1) * 68 + arow] = pack2(ax, ay);
    AtU[((ak4 >> 1) + 1) * 68 + arow] = pack2(az, aw);
    if (tid < 128) {
      WsU[wkk2 * 68 + wc4 + 0] = pack2(w0.x, w1.x);
      WsU[wkk2 * 68 + wc4 + 1] = pack2(w0.y, w1.y);
      WsU[wkk2 * 68 + wc4 + 2] = pack2(w0.z, w1.z);
      WsU[wkk2 * 68 + wc4 + 3] = pack2(w0.w, w1.w);
    }
    __syncthreads();
    if (ks + 16 < 64) {
      size_t an = (size_t)(row0 + arow) * 256 + k0 + ks + 16 + ak4;
      p0 = ld4(&part[an]);
      p1 = ld4(&part[an + 262144]);
      p2 = ld4(&part[an + 524288]);
      p3 = ld4(&part[an + 786432]);
      if (tid < 128) {
        w0 = ld4(&W[(size_t)(k0 + ks + 16 + 2 * wkk2) * 256 + col0 + wc4]);
        w1 = ld4(&W[(size_t)(k0 + ks + 16 + 2 * wkk2 + 1) * 256 + col0 + wc4]);
      }
    }
#pragma unroll
    for (int kk2 = 0; kk2 < 8; ++kk2) {
      uint4 a4 = *reinterpret_cast<const uint4*>(&AtU[kk2 * 68 + ty * 4]);
      uint4 w4 = *reinterpret_cast<const uint4*>(&WsU[kk2 * 68 + tx * 4]);
      acc[0][0] = dot2(a4.x, w4.x, acc[0][0]); acc[0][1] = dot2(a4.x, w4.y, acc[0][1]);
      acc[0][2] = dot2(a4.x, w4.z, acc[0][2]); acc[0][3] = dot2(a4.x, w4.w, acc[0][3]);
      acc[1][0] = dot2(a4.y, w4.x, acc[1][0]); acc[1][1] = dot2(a4.y, w4.y, acc[1][1]);
      acc[1][2] = dot2(a4.y, w4.z, acc[1][2]); acc[1][3] = dot2(a4.y, w4.w, acc[1][3]);
      acc[2][0] = dot2(a4.z, w4.x, acc[2][0]); acc[2][1] = dot2(a4.z, w4.y, acc[2][1]);
      acc[2][2] = dot2(a4.z, w4.z, acc[2][2]); acc[2][3] = dot2(a4.z, w4.w, acc[2][3]);
      acc[3][0] = dot2(a4.w, w4.x, acc[3][0]); acc[3][1] = dot2(a4.w, w4.y, acc[3][1]);
      acc[3][2] = dot2(a4.w, w4.z, acc[3][2]); acc[3][3] = dot2(a4.w, w4.w, acc[3][3]);
    }
  }
#pragma unroll
  for (int i = 0; i < 4; ++i) {
    float4 o = {acc[i][0], acc[i][1], acc[i][2], acc[i][3]};
    st4(&dst[(size_t)(row0 + ty * 4 + i) * 256 + col0 + tx * 4], o);
  }
}

__device__ __forceinline__ void wred2(float& s, float& q) {
#pragma unroll
  for (int off = 32; off; off >>= 1) {
    s += __shfl_xor(s, off);
    q += __shfl_xor(q, off);
  }
}

// ---- colmean(64-col slice of X) + mean-linear partial (f32).
__device__ __forceinline__ void mtk_dev(float* lds, const float* __restrict__ X,
                                        const float* __restrict__ Wl,
                                        const float* __restrict__ bias,
                                        float* __restrict__ mtp, int gb, int ks, int Kd) {
  float* sm = lds;
  float* m64 = lds + 256;
  const int tid = threadIdx.x;
  const int col = tid & 63, q = tid >> 6;
  const float* xb = X + (size_t)(gb * 256 + q * 64) * Kd + ks * 64 + col;
  float s = 0.f;
#pragma unroll 8
  for (int r = 0; r < 64; ++r) s += xb[(size_t)r * Kd];
  sm[tid] = s;
  __syncthreads();
  if (tid < 64) m64[tid] = (sm[tid] + sm[tid + 64] + sm[tid + 128] + sm[tid + 192]) * (1.f / 256.f);
  __syncthreads();
  const int c = tid;
  float acc = (ks == 0) ? bias[c] : 0.f;
  const float* wp = Wl + (size_t)ks * 64 * 256 + c;
#pragma unroll 8
  for (int k = 0; k < 64; ++k) acc = fmaf(m64[k], wp[(size_t)k * 256], acc);
  mtp[((size_t)(ks * 4 + gb) << 8) + c] = acc;
}

// ---- colmean of h1 (recomputed inline: relu(sum part slabs + mt1)) + W2l partial (f32).
__device__ __forceinline__ void mtk_h1(float* lds, const float* __restrict__ part,
                                       const float* __restrict__ mt1p,
                                       const float* __restrict__ Wl,
                                       const float* __restrict__ bias,
                                       float* __restrict__ mtp, int gb, int ks) {
  float* sm = lds;
  float* m64 = lds + 256;
  const int tid = threadIdx.x;
  const int col = tid & 63, q = tid >> 6;
  float mt1v = 0.f;
#pragma unroll
  for (int k2 = 0; k2 < 12; ++k2) mt1v += mt1p[((size_t)(k2 * 4 + gb) << 8) + ks * 64 + col];
  const float* pb = part + (size_t)(gb * 256 + q * 64) * 256 + ks * 64 + col;
  float s = 0.f;
#pragma unroll 4
  for (int r = 0; r < 64; ++r) {
    size_t o = (size_t)r * 256;
    float v = pb[o] + pb[o + 262144] + pb[o + 524288] + pb[o + 786432] + mt1v;
    s += fmaxf(v, 0.f);
  }
  sm[tid] = s;
  __syncthreads();
  if (tid < 64) m64[tid] = (sm[tid] + sm[tid + 64] + sm[tid + 128] + sm[tid + 192]) * (1.f / 256.f);
  __syncthreads();
  const int c = tid;
  float acc = (ks == 0) ? bias[c] : 0.f;
  const float* wp = Wl + (size_t)ks * 64 * 256 + c;
#pragma unroll 8
  for (int k = 0; k < 64; ++k) acc = fmaf(m64[k], wp[(size_t)k * 256], acc);
  mtp[((size_t)(ks * 4 + gb) << 8) + c] = acc;
}

// ================== kernels ==================

// gemm: grid (16 mtiles, 4 ntiles, KS), block 256.
__global__ __launch_bounds__(256) void k_gemm(const float* __restrict__ A,
                                              const float* __restrict__ W,
                                              const float* __restrict__ bias,
                                              float* __restrict__ dst,
                                              int K, int chunk) {
  __shared__ unsigned ldsU[1088];
  float* base = bias ? dst : dst + (size_t)blockIdx.z * 262144;
  gemm16(ldsU, A, W, bias, base, K, chunk,
         blockIdx.x * 64, blockIdx.y * 64, blockIdx.z * chunk);
}

// merged P0+P1 for iter 0: grid 320 1-D. b<256: xp partials (v_t@Wx). b>=256: x_in.
__global__ __launch_bounds__(256) void k_gemm0(const float* __restrict__ v_t,
                                               const float* __restrict__ Wx,
                                               float* __restrict__ part,
                                               const float* __restrict__ inputs,
                                               const float* __restrict__ Wp,
                                               const float* __restrict__ bp,
                                               float* __restrict__ x_in) {
  __shared__ unsigned ldsU[1088];
  const int b = blockIdx.x;
  if (b < 256) {
    int mt = b & 15, ntile = (b >> 4) & 3, kz = b >> 6;
    gemm16(ldsU, v_t, Wx, nullptr, part + (size_t)kz * 262144, 256, 64,
           mt * 64, ntile * 64, kz * 64);
  } else {
    int idx = b - 256;  // 0..63
    int mt = idx & 15, ntile = idx >> 4;
    gemm16(ldsU, inputs, Wp, bp, x_in, 128, 128, mt * 64, ntile * 64, 0);
  }
}

// fused adjacency (f32, verified): grid (8, 8, 4), block 256.
__global__ __launch_bounds__(256) void k_adj(const float* __restrict__ part,
                                             const float* __restrict__ incold,
                                             const float* __restrict__ wi,
                                             const float* __restrict__ bi,
                                             const float* __restrict__ bx,
                                             const float* __restrict__ wsv,
                                             const float* __restrict__ bs,
                                             float* __restrict__ pred,
                                             float* __restrict__ pred2) {
  __shared__ float lds[8448];
  float* tn = lds;
  float* te = lds + 32 * 132;
  const int n0 = blockIdx.x * 32, e0 = blockIdx.y * 32, gb = blockIdx.z;
  const int tid = threadIdx.x;
  const size_t rb = (size_t)gb * 256;
  const int tx = tid & 15, ty = tid >> 4;
  float incv[2][2], acc[2][2];
#pragma unroll
  for (int j = 0; j < 2; ++j)
#pragma unroll
    for (int i = 0; i < 2; ++i) {
      incv[j][i] = incold[((rb + e0 + ty + 16 * j) << 8) + n0 + tx + 16 * i];
      acc[j][i] = 0.f;
    }
  for (int dh = 0; dh < 256; dh += 128) {
    if (dh) __syncthreads();
#pragma unroll
    for (int s = 0; s < 4; ++s) {
      int idx = tid + s * 256;
      int row = idx >> 5;
      int d = dh + (idx & 31) * 4;
      float4 bxv = ld4(&bx[d]);
      {
        size_t o = ((rb + n0 + row) << 8) + d;
        float4 p0 = ld4(&part[o]);
        float4 p1 = ld4(&part[o + 262144]);
        float4 p2 = ld4(&part[o + 524288]);
        float4 p3 = ld4(&part[o + 786432]);
        float4 v;
        v.x = p0.x + p1.x + p2.x + p3.x + bxv.x;
        v.y = p0.y + p1.y + p2.y + p3.y + bxv.y;
        v.z = p0.z + p1.z + p2.z + p3.z + bxv.z;
        v.w = p0.w + p1.w + p2.w + p3.w + bxv.w;
        st4(&tn[row * 132 + (d - dh)], v);
      }
      {
        size_t o = ((rb + e0 + row) << 8) + d;
        float4 p0 = ld4(&part[o]);
        float4 p1 = ld4(&part[o + 262144]);
        float4 p2 = ld4(&part[o + 524288]);
        float4 p3 = ld4(&part[o + 786432]);
        float4 bv = ld4(&bi[d]);
        float4 v;
        v.x = p0.x + p1.x + p2.x + p3.x + bxv.x + bv.x;
        v.y = p0.y + p1.y + p2.y + p3.y + bxv.y + bv.y;
        v.z = p0.z + p1.z + p2.z + p3.z + bxv.z + bv.z;
        v.w = p0.w + p1.w + p2.w + p3.w + bxv.w + bv.w;
        st4(&te[row * 132 + (d - dh)], v);
      }
    }
    __syncthreads();
#pragma unroll 4
    for (int dl = 0; dl < 128; dl += 4) {
      float4 wiq = ld4(&wi[dh + dl]);
      float4 wsq = ld4(&wsv[dh + dl]);
      float4 xn0 = ld4(&tn[tx * 132 + dl]);
      float4 xn1 = ld4(&tn[(tx + 16) * 132 + dl]);
      float4 xe0 = ld4(&te[ty * 132 + dl]);
      float4 xe1 = ld4(&te[(ty + 16) * 132 + dl]);
#pragma unroll
      for (int j = 0; j < 2; ++j) {
        float4 xe = j ? xe1 : xe0;
#pragma unroll
        for (int i = 0; i < 2; ++i) {
          float4 xn = i ? xn1 : xn0;
          float u;
          u = fmaf(incv[j][i], wiq.x, xn.x + xe.x); u = fmaxf(u, 0.f); acc[j][i] = fmaf(u, wsq.x, acc[j][i]);
          u = fmaf(incv[j][i], wiq.y, xn.y + xe.y); u = fmaxf(u, 0.f); acc[j][i] = fmaf(u, wsq.y, acc[j][i]);
          u = fmaf(incv[j][i], wiq.z, xn.z + xe.z); u = fmaxf(u, 0.f); acc[j][i] = fmaf(u, wsq.z, acc[j][i]);
          u = fmaf(incv[j][i], wiq.w, xn.w + xe.w); u = fmaxf(u, 0.f); acc[j][i] = fmaf(u, wsq.w, acc[j][i]);
        }
      }
    }
  }
  const float b0 = bs[0];
#pragma unroll
  for (int j = 0; j < 2; ++j)
#pragma unroll
    for (int i = 0; i < 2; ++i) {
      float s = acc[j][i] + b0;
      float v = 1.f / (1.f + __expf(-s));
      size_t o = ((rb + e0 + ty + 16 * j) << 8) + n0 + tx + 16 * i;
      pred[o] = v;
      if (pred2) pred2[o] = v;
    }
}

// transposed-A GEMM: grid (4 ntiles, 4 ctiles, 16 = gb*4+kc), block 256.
__global__ __launch_bounds__(256) void k_gemmt(const float* __restrict__ pred,
                                               const float* __restrict__ nt,
                                               float* __restrict__ part) {
  __shared__ unsigned ldsU[1088];
  const int gb = blockIdx.z >> 2, kc = blockIdx.z & 3;
  gemmt16(ldsU, pred, nt, part + (size_t)kc * 262144,
          gb, blockIdx.x * 64, blockIdx.y * 64, kc * 64);
}

// reduce upd partials + LN(concat) -> h. grid 256, block 256.
__global__ __launch_bounds__(256) void k_ln768(const float* __restrict__ part,
                                               const float* __restrict__ x_in,
                                               const float* __restrict__ nt,
                                               const float* __restrict__ g,
                                               const float* __restrict__ be,
                                               float* __restrict__ h) {
  const int row = blockIdx.x * 4 + (threadIdx.x >> 6);
  const int lane = threadIdx.x & 63;
  const int c4 = lane * 4;
  const size_t ro = (size_t)row * 256 + c4;
  float4 u = ld4(&part[ro]);
  float4 u1 = ld4(&part[ro + 262144]);
  float4 u2 = ld4(&part[ro + 524288]);
  float4 u3 = ld4(&part[ro + 786432]);
  u.x += u1.x + u2.x + u3.x;
  u.y += u1.y + u2.y + u3.y;
  u.z += u1.z + u2.z + u3.z;
  u.w += u1.w + u2.w + u3.w;
  float4 xi = ld4(&x_in[ro]);
  float4 nv = ld4(&nt[ro]);
  float s = xi.x + xi.y + xi.z + xi.w + nv.x + nv.y + nv.z + nv.w + u.x + u.y + u.z + u.w;
  float sq = xi.x * xi.x + xi.y * xi.y + xi.z * xi.z + xi.w * xi.w
           + nv.x * nv.x + nv.y * nv.y + nv.z * nv.z + nv.w * nv.w
           + u.x * u.x + u.y * u.y + u.z * u.z + u.w * u.w;
  wred2(s, sq);
  float mu = s * (1.f / 768.f);
  float rs = rsqrtf(sq * (1.f / 768.f) - mu * mu + LN_EPS);
  float* hr = h + (size_t)row * 768;
  {
    float4 g4 = ld4(&g[c4]), b4 = ld4(&be[c4]), o;
    o.x = (xi.x - mu) * rs * g4.x + b4.x;
    o.y = (xi.y - mu) * rs * g4.y + b4.y;
    o.z = (xi.z - mu) * rs * g4.z + b4.z;
    o.w = (xi.w - mu) * rs * g4.w + b4.w;
    st4(&hr[c4], o);
  }
  {
    float4 g4 = ld4(&g[256 + c4]), b4 = ld4(&be[256 + c4]), o;
    o.x = (nv.x - mu) * rs * g4.x + b4.x;
    o.y = (nv.y - mu) * rs * g4.y + b4.y;
    o.z = (nv.z - mu) * rs * g4.z + b4.z;
    o.w = (nv.w - mu) * rs * g4.w + b4.w;
    st4(&hr[256 + c4], o);
  }
  {
    float4 g4 = ld4(&g[512 + c4]), b4 = ld4(&be[512 + c4]), o;
    o.x = (u.x - mu) * rs * g4.x + b4.x;
    o.y = (u.y - mu) * rs * g4.y + b4.y;
    o.z = (u.z - mu) * rs * g4.z + b4.z;
    o.w = (u.w - mu) * rs * g4.w + b4.w;
    st4(&hr[512 + c4], o);
  }
}

// gemm768 (h @ W1g -> part) + mt1 partials, 1-D grid 304, block 256.
__global__ __launch_bounds__(256) void k_g768mtk(const float* __restrict__ h,
                                                 const float* __restrict__ W1g,
                                                 const float* __restrict__ W1l,
                                                 const float* __restrict__ b1,
                                                 float* __restrict__ part,
                                                 float* __restrict__ mt1p) {
  __shared__ unsigned ldsU[1088];
  const int b = blockIdx.x;
  if (b < 256) {
    int mt = b & 15, ntile = (b >> 4) & 3, kz = b >> 6;
    gemm16(ldsU, h, W1g, nullptr, part + (size_t)kz * 262144, 768, 192,
           mt * 64, ntile * 64, kz * 192);
  } else {
    int idx = b - 256;           // 0..47
    mtk_dev(reinterpret_cast<float*>(ldsU), h, W1l, b1, mt1p, idx & 3, idx >> 2, 768);
  }
}

// gemm_h1 (relu(h1) @ W2g -> part2) + mt2 partials, 1-D grid 272, block 256.
__global__ __launch_bounds__(256) void k_gh1mtk2(const float* __restrict__ part,
                                                 const float* __restrict__ mt1p,
                                                 const float* __restrict__ W2g,
                                                 const float* __restrict__ W2l,
                                                 const float* __restrict__ b2,
                                                 float* __restrict__ part2,
                                                 float* __restrict__ mt2p) {
  __shared__ unsigned ldsU[1152];
  const int b = blockIdx.x;
  if (b < 256) {
    int mt = b & 15, ntile = (b >> 4) & 3, kz = b >> 6;
    gemm_h116(ldsU, part, mt1p, W2g, part2 + (size_t)kz * 262144,
              mt >> 2, mt * 64, ntile * 64, kz * 64);
  } else {
    int idx = b - 256;           // 0..15
    mtk_h1(reinterpret_cast<float*>(ldsU), part, mt1p, W2l, b2, mt2p, idx & 3, idx >> 2);
  }
}

// reduce part2 partials + mt2 + residual + LN -> dst. grid 256, block 256.
__global__ __launch_bounds__(256) void k_ln256(const float* __restrict__ part2,
                                               const float* __restrict__ nt,
                                               const float* __restrict__ mt2p,
                                               const float* __restrict__ g,
                                               const float* __restrict__ be,
                                               float* __restrict__ dst) {
  const int row = blockIdx.x * 4 + (threadIdx.x >> 6);
  const int lane = threadIdx.x & 63;
  const int c4 = lane * 4;
  const int gb = row >> 8;
  const size_t ro = (size_t)row * 256 + c4;
  float4 p0 = ld4(&part2[ro]);
  float4 p1 = ld4(&part2[ro + 262144]);
  float4 p2 = ld4(&part2[ro + 524288]);
  float4 p3 = ld4(&part2[ro + 786432]);
  float4 m4 = {0.f, 0.f, 0.f, 0.f};
#pragma unroll
  for (int k2 = 0; k2 < 4; ++k2) {
    float4 mv = ld4(&mt2p[((size_t)(k2 * 4 + gb) << 8) + c4]);
    m4.x += mv.x; m4.y += mv.y; m4.z += mv.z; m4.w += mv.w;
  }
  float4 nv = ld4(&nt[ro]);
  float4 x;
  x.x = nv.x + p0.x + p1.x + p2.x + p3.x + m4.x;
  x.y = nv.y + p0.y + p1.y + p2.y + p3.y + m4.y;
  x.z = nv.z + p0.z + p1.z + p2.z + p3.z + m4.z;
  x.w = nv.w + p0.w + p1.w + p2.w + p3.w + m4.w;
  float s = x.x + x.y + x.z + x.w;
  float sq = x.x * x.x + x.y * x.y + x.z * x.z + x.w * x.w;
  wred2(s, sq);
  float mu = s * (1.f / 256.f);
  float rs = rsqrtf(sq * (1.f / 256.f) - mu * mu + LN_EPS);
  float4 g4 = ld4(&g[c4]), b4 = ld4(&be[c4]), o;
  o.x = (x.x - mu) * rs * g4.x + b4.x;
  o.y = (x.y - mu) * rs * g4.y + b4.y;
  o.z = (x.z - mu) * rs * g4.z + b4.z;
  o.w = (x.w - mu) * rs * g4.w + b4.w;
  st4(&dst[ro], o);
}

extern "C" void kernel_launch(void* const* d_in, const int* in_sizes, int n_in,
                              void* d_out, int out_size, void* d_ws, size_t ws_size,
                              hipStream_t stream) {
  (void)in_sizes; (void)n_in; (void)out_size; (void)ws_size;
  const float* inputs = (const float*)d_in[0];
  const float* v_t    = (const float*)d_in[1];
  const float* i_t    = (const float*)d_in[2];
  const float* Wp     = (const float*)d_in[3];
  const float* bp     = (const float*)d_in[4];
  const float* Wx     = (const float*)d_in[5];
  const float* bx     = (const float*)d_in[6];
  const float* wi     = (const float*)d_in[7];
  const float* bi     = (const float*)d_in[8];
  const float* ws     = (const float*)d_in[9];
  const float* bs     = (const float*)d_in[10];
  const float* g_pre  = (const float*)d_in[11];
  const float* be_pre = (const float*)d_in[12];
  const float* g_n    = (const float*)d_in[13];
  const float* be_n   = (const float*)d_in[14];
  const float* W1g    = (const float*)d_in[15];
  const float* W1l    = (const float*)d_in[16];
  const float* b1     = (const float*)d_in[17];
  const float* W2g    = (const float*)d_in[18];
  const float* W2l    = (const float*)d_in[19];
  const float* b2     = (const float*)d_in[20];
  float* out = (float*)d_out;
  float* wsf = (float*)d_ws;
  float* x_in  = wsf;                  // 1 MB
  float* ntA   = wsf + 262144;         // 1 MB
  float* ntB   = wsf + 524288;         // 1 MB
  float* h     = wsf + 786432;         // 3 MB (dead after k_g768mtk)
  float* part2 = wsf + 786432;         // 4 MB = h + old-h1 region
  float* part  = wsf + 1835008;        // 4 MB
  float* mt1p  = wsf + 2883584;        // 48 KB
  float* mt2p  = wsf + 2895872;        // 16 KB

  for (int t = 0; t < 3; ++t) {
    const float* ntCur = (t == 0) ? v_t : ((t == 1) ? ntA : ntB);
    float* dstNt = (t == 2) ? (out + 786432) : ((t == 0) ? ntA : ntB);
    const float* incold = (t == 0) ? i_t : (out + (size_t)(t - 1) * 262144);
    float* pred = out + (size_t)t * 262144;
    float* pred2 = (t == 2) ? (out + 1048576) : nullptr;

    // P1: xp partials = ntCur @ Wx (K-split 4); at t=0 also x_in as extra blocks
    if (t == 0) {
      k_gemm0<<<320, 256, 0, stream>>>(v_t, Wx, part, inputs, Wp, bp, x_in);
    } else {
      k_gemm<<<dim3(16, 4, 4), 256, 0, stream>>>(ntCur, Wx, nullptr, part, 256, 64);
    }
    // P2: inc = sigmoid(sum_d relu(xp[n]+xp[e]+bi + inc*wi) * ws + bs)
    k_adj<<<dim3(8, 8, 4), 256, 0, stream>>>(part, incold, wi, bi, bx, ws, bs, pred, pred2);
    // P3: upd partials = pred^T @ ntCur (e-split 4)
    k_gemmt<<<dim3(4, 4, 16), 256, 0, stream>>>(pred, ntCur, part);
    // P4: h = LN(concat(x_in, nt, upd))
    k_ln768<<<256, 256, 0, stream>>>(part, x_in, ntCur, g_pre, be_pre, h);
    // P5: gemm768 partials + mt1 partials (one dispatch)
    k_g768mtk<<<304, 256, 0, stream>>>(h, W1g, W1l, b1, part, mt1p);
    // P6: part2 partials = relu(h1 inline) @ W2g + mt2 partials (one dispatch)
    k_gh1mtk2<<<272, 256, 0, stream>>>(part, mt1p, W2g, W2l, b2, part2, mt2p);
    // P7: nt' = LN(nt + sum part2 + mt2)
    k_ln256<<<256, 256, 0, stream>>>(part2, ntCur, mt2p, g_n, be_n, dstNt);
  }
}